// Round 2
// baseline (241.884 us; speedup 1.0000x reference)
//
#include <hip/hip_runtime.h>
#include <hip/hip_bf16.h>

// Problem constants (from reference): B=8, T=4096, E=16, H=64
#define BB 8
#define TT 4096
#define EE 16
#define HH 64
#define ZT 8       // colsum t-chunk split (atomic-free partials)

typedef __attribute__((ext_vector_type(8))) __bf16 bf16x8;  // MFMA A/B frag (4 VGPRs)
typedef __attribute__((ext_vector_type(4))) __bf16 bf16x4;  // packed E write (8B)
typedef __attribute__((ext_vector_type(4))) float f32x4;    // MFMA C/D frag

// e^(d^(-1/16)) ≈ P4(log2(d) - 5.5): degree-4 Taylor of exp(2^(-u/16)) about
// u=5.5. |rel err| < 2.5e-4 for d ∈ [2,1024] — inside bf16 noise (validated
// R6/R7: absmax identical to 3-transcendental version). 1 transc + 5 VALU.
static __device__ __forceinline__ float exp_pow16(float d) {
    float t = __builtin_amdgcn_logf(d) - 5.5f;     // v_log_f32 = log2
    float r = __builtin_fmaf(t, 2.72889e-6f, -9.35716e-5f);
    r = __builtin_fmaf(t, r, 2.90736e-3f);
    r = __builtin_fmaf(t, r, -7.50656e-2f);
    r = __builtin_fmaf(t, r, 2.198967f);
    return r;
}

// ---- kernel 1: Qb = bf16(x@Wq), Kb = bf16(x@Wk) ----------------------------
__global__ __launch_bounds__(256) void proj_kernel(
        const float* __restrict__ x, const float* __restrict__ Wq,
        const float* __restrict__ Wk,
        __bf16* __restrict__ Qb, __bf16* __restrict__ Kb) {
    int tid = threadIdx.x;
    int row = blockIdx.x * 4 + (tid >> 6);
    int h = tid & 63;
    const float* xr = x + (size_t)row * EE;
    float q = 0.f, k = 0.f;
#pragma unroll
    for (int e = 0; e < EE; ++e) {
        float xv = xr[e];
        q += xv * Wq[e * HH + h];
        k += xv * Wk[e * HH + h];
    }
    size_t idx = (size_t)row * HH + h;
    Qb[idx] = (__bf16)q;
    Kb[idx] = (__bf16)k;
}

// ---- kernel 2: Dpart[z][b][s] = sum_{t in chunk z} exp((q_t.k_s)^(-1/16)) --
// R10: zero LDS, zero barriers. K fragments persistent in regs (wave owns 64 s);
// Q A-fragments are 16B-contiguous global rows -> direct global_load_dwordx4,
// register double-buffered (unroll-2). The 4-wave redundant Q reads hit L1
// (4KB/iter working set); waves free-run with no sync points.
__global__ __launch_bounds__(256, 4) void colsum_mfma(
        const __bf16* __restrict__ Qb, const __bf16* __restrict__ Kb,
        float* __restrict__ Dpart) {
    int lane = threadIdx.x & 63;
    int w = threadIdx.x >> 6;
    int quad = lane >> 4;
    int l15 = lane & 15;
    int b = blockIdx.y;
    int z = blockIdx.z;
    int s0 = blockIdx.x * 256 + w * 64;

    const __bf16* Qbb = Qb + (size_t)b * TT * HH;
    const __bf16* Kbb = Kb + (size_t)b * TT * HH;

    bf16x8 bk[4][2];
#pragma unroll
    for (int st = 0; st < 4; ++st) {
        const __bf16* krow = Kbb + (size_t)(s0 + st * 16 + l15) * HH + quad * 8;
        bk[st][0] = *(const bf16x8*)(krow);
        bk[st][1] = *(const bf16x8*)(krow + 32);
    }

    // A-frag source: A[m=t][k=h]: lane (quad,l15) reads Q[t=base+ts*16+l15]
    // [h = quad*8 .. +7 (+kh*32)] = 16B contiguous
    const __bf16* gq = Qbb + (size_t)l15 * HH + quad * 8;

    const int TL = TT / ZT;                  // 512 t per block
    int t0 = z * TL, tend = t0 + TL;

    float csum[4] = {0.f, 0.f, 0.f, 0.f};

    auto LOADQ = [&](bf16x8 aq[2][2], int t) {
        const __bf16* p = gq + (size_t)t * HH;
#pragma unroll
        for (int ts = 0; ts < 2; ++ts)
#pragma unroll
            for (int kh = 0; kh < 2; ++kh)
                aq[ts][kh] = *(const bf16x8*)(p + ts * 16 * HH + kh * 32);
    };
    auto BODY = [&](bf16x8 aq[2][2]) {
#pragma unroll
        for (int st = 0; st < 4; ++st) {
            f32x4 c0 = {0.f, 0.f, 0.f, 0.f};
            f32x4 c1 = {0.f, 0.f, 0.f, 0.f};
            c0 = __builtin_amdgcn_mfma_f32_16x16x32_bf16(aq[0][0], bk[st][0], c0, 0, 0, 0);
            c1 = __builtin_amdgcn_mfma_f32_16x16x32_bf16(aq[1][0], bk[st][0], c1, 0, 0, 0);
            c0 = __builtin_amdgcn_mfma_f32_16x16x32_bf16(aq[0][1], bk[st][1], c0, 0, 0, 0);
            c1 = __builtin_amdgcn_mfma_f32_16x16x32_bf16(aq[1][1], bk[st][1], c1, 0, 0, 0);
            csum[st] += exp_pow16(c0[0]) + exp_pow16(c0[1])
                      + exp_pow16(c0[2]) + exp_pow16(c0[3])
                      + exp_pow16(c1[0]) + exp_pow16(c1[1])
                      + exp_pow16(c1[2]) + exp_pow16(c1[3]);
        }
    };

    bf16x8 aqA[2][2], aqB[2][2];
    LOADQ(aqA, t0);
    for (int t = t0; t < tend; t += 64) {     // TL % 64 == 0
        LOADQ(aqB, t + 32);
        BODY(aqA);
        int tn = (t + 64 < tend) ? (t + 64) : t0;   // last iter: dummy reload
        LOADQ(aqA, tn);
        BODY(aqB);
    }

#pragma unroll
    for (int st = 0; st < 4; ++st) {
        float r = csum[st];
        r += __shfl_xor(r, 16, 64);           // sum across quads (t-rows)
        r += __shfl_xor(r, 32, 64);
        if (quad == 0)
            Dpart[((size_t)z * BB + b) * TT + s0 + st * 16 + l15] = r;
    }
}

// ---- kernel 3: VsT[b][h][s] = bf16(Kb[b][s][h]) / sum_z Dpart[z][b][s] -----
__global__ __launch_bounds__(256) void vscale_kernel(
        const __bf16* __restrict__ Kb, const float* __restrict__ Dpart,
        __bf16* __restrict__ VsT) {
    __shared__ float tile[64][65];
    __shared__ float Rs[64];                  // 1/D per s_local
    int b = blockIdx.y;
    int s0 = blockIdx.x * 64;
    int c = threadIdx.x & 63;
    int rr = threadIdx.x >> 6;
    if (threadIdx.x < 64) {
        size_t si = (size_t)b * TT + s0 + threadIdx.x;
        float d = Dpart[si];
#pragma unroll
        for (int zz = 1; zz < ZT; ++zz) d += Dpart[(size_t)zz * BB * TT + si];
        Rs[threadIdx.x] = 1.0f / d;
    }
    __syncthreads();
    const __bf16* Kbase = Kb + ((size_t)b * TT + s0) * HH;
#pragma unroll
    for (int i = rr; i < 64; i += 4)
        tile[i][c] = (float)Kbase[(size_t)i * HH + c] * Rs[i];   // tile[s_local][h]
    __syncthreads();
    __bf16* Vb = VsT + (size_t)b * HH * TT;
#pragma unroll
    for (int i = rr; i < 64; i += 4)
        Vb[(size_t)i * TT + s0 + c] = (__bf16)tile[c][i];        // VsT[h=i][s=s0+c]
}

// ---- kernel 4: OP[z][b][t][h] = sum_{s in slice z} exp(S_ts) * VsT[h][s] ---
// R8: QK MFMA computes S^T (A=K, B=Q); C rows are s = quad*4+r so the E[t][s]
// transpose write is one packed ds_write_b64 per (tile,sub).
// R10: drop ALL global->LDS staging and ALL barriers. K fragments (A of QK^T)
// and V fragments (B of PV) are 16B-contiguous global rows -> direct
// global_load_dwordx4, register double-buffered (unroll-2). Only the per-wave
// Etile transpose round-trip remains in LDS (private: no inter-wave sync).
// L1 absorbs the 4-wave redundancy (8KB/iter working set); 32 t-blocks with
// the same (b,z) share K/V slabs in L2.
__global__ __launch_bounds__(256, 3) void out_mfma(
        const __bf16* __restrict__ Qb, const __bf16* __restrict__ Kb,
        const __bf16* __restrict__ VsT, float* __restrict__ OP) {
    __shared__ __bf16 Etile[4][2][16 * 40]; // per-wave, per-tile E[t 16][s 32+pad8]

    int lane = threadIdx.x & 63;
    int w = threadIdx.x >> 6;
    int quad = lane >> 4;
    int l15 = lane & 15;
    int b = blockIdx.y;
    int z = blockIdx.z;
    int t0 = blockIdx.x * 128 + w * 32;

    const __bf16* Qbb = Qb + (size_t)b * TT * HH;
    const __bf16* Kbb = Kb + (size_t)b * TT * HH;
    const __bf16* Vbb = VsT + (size_t)b * HH * TT;

    bf16x8 aq[2][2];                        // Q B-operand frags, persistent
#pragma unroll
    for (int tile = 0; tile < 2; ++tile) {
        const __bf16* qrow = Qbb + (size_t)(t0 + tile * 16 + l15) * HH + quad * 8;
        aq[tile][0] = *(const bf16x8*)(qrow);
        aq[tile][1] = *(const bf16x8*)(qrow + 32);
    }

    f32x4 acc[2][4];
#pragma unroll
    for (int tile = 0; tile < 2; ++tile)
#pragma unroll
        for (int ht = 0; ht < 4; ++ht)
            acc[tile][ht] = (f32x4){0.f, 0.f, 0.f, 0.f};

    // K A-frag: lane (quad,l15) reads K[s=base+sub*16+l15][h=quad*8..+7 (+kh*32)]
    const __bf16* gk = Kbb + (size_t)l15 * HH + quad * 8;
    // V B-frag: lane (quad,l15) reads VsT[h=ht*16+l15][s=base+quad*8..+7]
    const __bf16* gv = Vbb + (size_t)l15 * TT + quad * 8;

    const int SL = TT / gridDim.z;
    int s0z = z * SL, send = s0z + SL;

    auto LOADK = [&](bf16x8 bk[2][2], int s) {
        const __bf16* p = gk + (size_t)s * HH;
#pragma unroll
        for (int sub = 0; sub < 2; ++sub)
#pragma unroll
            for (int kh = 0; kh < 2; ++kh)
                bk[sub][kh] = *(const bf16x8*)(p + sub * 16 * HH + kh * 32);
    };
    auto LOADV = [&](bf16x8 bv[4], int s) {
#pragma unroll
        for (int ht = 0; ht < 4; ++ht)
            bv[ht] = *(const bf16x8*)(gv + (size_t)ht * 16 * TT + s);
    };
    auto BODY = [&](bf16x8 bk[2][2], bf16x8 bv[4]) {
#pragma unroll
        for (int tile = 0; tile < 2; ++tile) {
#pragma unroll
            for (int sub = 0; sub < 2; ++sub) {
                // S^T: A=K (m=s), B=Q (n=t) -> row = s_local = quad*4+r,
                // col = t_local = l15. 4 regs = 4 consecutive s.
                f32x4 c = {0.f, 0.f, 0.f, 0.f};
                c = __builtin_amdgcn_mfma_f32_16x16x32_bf16(bk[sub][0], aq[tile][0], c, 0, 0, 0);
                c = __builtin_amdgcn_mfma_f32_16x16x32_bf16(bk[sub][1], aq[tile][1], c, 0, 0, 0);
                bf16x4 e;
#pragma unroll
                for (int r = 0; r < 4; ++r)
                    e[r] = (__bf16)exp_pow16(c[r]);
                // E[t=l15][s = sub*16 + quad*4 .. +3]: one packed 8B write
                *(bf16x4*)&Etile[w][tile][l15 * 40 + sub * 16 + quad * 4] = e;
            }
        }
        // compiler inserts the lgkmcnt wait for the E write->read dependency;
        // same-wave DS ops execute in order so the WAR on the next call is safe
#pragma unroll
        for (int tile = 0; tile < 2; ++tile) {
            // A-frag from E: A[m=t=l15][k=s=quad*8+j] — contiguous b128
            bf16x8 aE = *(const bf16x8*)&Etile[w][tile][l15 * 40 + quad * 8];
#pragma unroll
            for (int ht = 0; ht < 4; ++ht)
                acc[tile][ht] = __builtin_amdgcn_mfma_f32_16x16x32_bf16(aE, bv[ht], acc[tile][ht], 0, 0, 0);
        }
    };

    bf16x8 bkA[2][2], bvA[4], bkB[2][2], bvB[4];
    LOADK(bkA, s0z);
    LOADV(bvA, s0z);
    for (int s = s0z; s < send; s += 64) {    // SL % 64 == 0
        LOADK(bkB, s + 32);
        LOADV(bvB, s + 32);
        BODY(bkA, bvA);
        int sn = (s + 64 < send) ? (s + 64) : s0z;   // last iter: dummy reload
        LOADK(bkA, sn);
        LOADV(bvA, sn);
        BODY(bkB, bvB);
    }

    float* op = OP + (((size_t)z * BB + b) * TT + t0) * HH;
#pragma unroll
    for (int tile = 0; tile < 2; ++tile) {
#pragma unroll
        for (int r = 0; r < 4; ++r) {
            size_t ro = (size_t)(tile * 16 + quad * 4 + r) * HH + l15;
            op[ro]      = acc[tile][0][r];
            op[ro + 16] = acc[tile][1][r];
            op[ro + 32] = acc[tile][2][r];
            op[ro + 48] = acc[tile][3][r];
        }
    }
}

// ---- kernel 5: out = sum_z OP[z] -------------------------------------------
__global__ __launch_bounds__(256) void reduce_kernel(
        const float* __restrict__ OP, float* __restrict__ out, int nslice) {
    size_t i = (size_t)blockIdx.x * 256 + threadIdx.x;   // float4 units
    const size_t N4 = (size_t)BB * TT * HH / 4;
    if (i >= N4) return;
    const float4* p = (const float4*)OP;
    float4 a = p[i];
    for (int zz = 1; zz < nslice; ++zz) {
        float4 v = p[(size_t)zz * N4 + i];
        a.x += v.x; a.y += v.y; a.z += v.z; a.w += v.w;
    }
    ((float4*)out)[i] = a;
}

extern "C" void kernel_launch(void* const* d_in, const int* in_sizes, int n_in,
                              void* d_out, int out_size, void* d_ws, size_t ws_size,
                              hipStream_t stream) {
    const float* x  = (const float*)d_in[0];
    const float* Wq = (const float*)d_in[1];
    const float* Wk = (const float*)d_in[2];
    // d_in[3] (Wv) unused: reference computes v = x @ Wk (faithful quirk).

    const size_t NE = (size_t)BB * TT * HH;     // 2,097,152
    size_t base = NE * 2 * 3 + (size_t)ZT * BB * TT * 4;
    int nslice = 4;
    if (base + (size_t)4 * NE * 4 > ws_size) nslice = 2;

    char* wp = (char*)d_ws;
    __bf16* Qb    = (__bf16*)wp;  wp += NE * 2;
    __bf16* Kb    = (__bf16*)wp;  wp += NE * 2;
    __bf16* VsT   = (__bf16*)wp;  wp += NE * 2;
    float*  Dpart = (float*)wp;   wp += (size_t)ZT * BB * TT * 4;
    float*  OP    = (float*)wp;
    float* out = (float*)d_out;

    proj_kernel<<<BB * TT / 4, 256, 0, stream>>>(x, Wq, Wk, Qb, Kb);
    colsum_mfma<<<dim3(TT / 256, BB, ZT), 256, 0, stream>>>(Qb, Kb, Dpart);
    vscale_kernel<<<dim3(TT / 64, BB), 256, 0, stream>>>(Kb, Dpart, VsT);
    out_mfma<<<dim3(TT / 128, BB, nslice), 256, 0, stream>>>(Qb, Kb, VsT, OP);
    reduce_kernel<<<(int)((NE / 4 + 255) / 256), 256, 0, stream>>>(OP, out, nslice);
}

// Round 3
// 168.744 us; speedup vs baseline: 1.4334x; 1.4334x over previous
//
#include <hip/hip_runtime.h>
#include <hip/hip_bf16.h>

// Problem constants (from reference): B=8, T=4096, E=16, H=64
#define BB 8
#define TT 4096
#define EE 16
#define HH 64
#define ZT 16      // colsum t-chunk split (atomic-free partials): 2048 blocks = 8/CU

typedef __attribute__((ext_vector_type(8))) __bf16 bf16x8;  // MFMA A/B frag (4 VGPRs)
typedef __attribute__((ext_vector_type(4))) __bf16 bf16x4;  // packed 8B
typedef __attribute__((ext_vector_type(4))) float f32x4;    // MFMA C/D frag

// e^(d^(-1/16)) ≈ P4(log2(d) - 5.5): degree-4 Taylor of exp(2^(-u/16)) about
// u=5.5. |rel err| < 2.5e-4 for d ∈ [2,1024] — inside bf16 noise (validated
// R6/R7). 1 transcendental + 5 VALU.
static __device__ __forceinline__ float exp_pow16(float d) {
    float t = __builtin_amdgcn_logf(d) - 5.5f;     // v_log_f32 = log2
    float r = __builtin_fmaf(t, 2.72889e-6f, -9.35716e-5f);
    r = __builtin_fmaf(t, r, 2.90736e-3f);
    r = __builtin_fmaf(t, r, -7.50656e-2f);
    r = __builtin_fmaf(t, r, 2.198967f);
    return r;
}

// ---- kernel 1: R11 rank-16 factorization -----------------------------------
// S = Q K^T = x (Wq Wk^T) x^T  — inner dim is E=16, not H=64.
// Yb = bf16(x @ M) with M = Wq Wk^T (computed per-block in LDS: 16k MACs,
// trivial), xb = bf16(x). Downstream QK^T uses S[t,s] = Y[t]·x[s] (K=16,
// zero-padded to the verified 16x16x32 intrinsic).
__global__ __launch_bounds__(256) void proj_kernel(
        const float* __restrict__ x, const float* __restrict__ Wq,
        const float* __restrict__ Wk,
        __bf16* __restrict__ Yb, __bf16* __restrict__ xb) {
    __shared__ float Ms[16][16];
    __shared__ float xs[16][16];
    int tid = threadIdx.x;
    int i = tid >> 4, j = tid & 15;
    float m = 0.f;
#pragma unroll 8
    for (int h = 0; h < HH; ++h) m += Wq[i * HH + h] * Wk[j * HH + h];
    Ms[i][j] = m;
    int row0 = blockIdx.x * 16;
    xs[i][j] = x[(size_t)(row0 + i) * EE + j];   // 256 consecutive floats
    __syncthreads();
    float y = 0.f;
#pragma unroll
    for (int k = 0; k < EE; ++k) y += xs[i][k] * Ms[k][j];
    size_t idx = (size_t)(row0 + i) * EE + j;
    Yb[idx] = (__bf16)y;
    xb[idx] = (__bf16)xs[i][j];
}

// ---- kernel 2: Dpart[z][b][s] = sum_{t in chunk z} exp((Y_t·x_s)^(-1/16)) --
// R11: zero LDS, zero barriers. Wave owns 64 s (4 persistent x B-frags, 8
// VGPR). Y streamed direct: the wave's frag-load covers a CONTIGUOUS 512B
// region (16 rows × 32B, quads 0-1 real / 2-3 zero-pad for K=32) — coalesced,
// unlike R10's 128B-strided pattern. 8 blocks/CU = 32 waves/CU; the exp chain
// (v_log at 1/4 rate) is the intended floor.
__global__ __launch_bounds__(256) void colsum_mfma(
        const __bf16* __restrict__ Yb, const __bf16* __restrict__ xb,
        float* __restrict__ Dpart) {
    int lane = threadIdx.x & 63;
    int w = threadIdx.x >> 6;
    int quad = lane >> 4;
    int l15 = lane & 15;
    int b = blockIdx.y;
    int z = blockIdx.z;
    int s0 = blockIdx.x * 256 + w * 64;

    const __bf16* xbb = xb + (size_t)b * TT * EE;
    const __bf16* Ybb = Yb + (size_t)b * TT * EE;

    // B[k=e][n=s]: lane holds xb[s0+st*16+l15][quad*8..+7]; k>=16 zero-padded
    bf16x8 bx[4];
#pragma unroll
    for (int st = 0; st < 4; ++st) {
        bf16x8 v = {};
        if (quad < 2)
            v = *(const bf16x8*)(xbb + (size_t)(s0 + st * 16 + l15) * EE + quad * 8);
        bx[st] = v;
    }

    const int TL = TT / ZT;                  // 256 t per block
    int t0 = z * TL, tend = t0 + TL;

    float csum[4] = {0.f, 0.f, 0.f, 0.f};
    for (int t = t0; t < tend; t += 32) {
        bf16x8 ya[2];                        // A[m=t][k=e], zero-padded k>=16
#pragma unroll
        for (int ts = 0; ts < 2; ++ts) {
            bf16x8 v = {};
            if (quad < 2)
                v = *(const bf16x8*)(Ybb + (size_t)(t + ts * 16 + l15) * EE + quad * 8);
            ya[ts] = v;
        }
#pragma unroll
        for (int st = 0; st < 4; ++st) {
#pragma unroll
            for (int ts = 0; ts < 2; ++ts) {
                f32x4 c = {0.f, 0.f, 0.f, 0.f};
                c = __builtin_amdgcn_mfma_f32_16x16x32_bf16(ya[ts], bx[st], c, 0, 0, 0);
                csum[st] += exp_pow16(c[0]) + exp_pow16(c[1])
                          + exp_pow16(c[2]) + exp_pow16(c[3]);
            }
        }
    }

    // C: row=t=quad*4+r (summed: in-reg + cross-quad shuffle), col=s=l15
#pragma unroll
    for (int st = 0; st < 4; ++st) {
        float r = csum[st];
        r += __shfl_xor(r, 16, 64);
        r += __shfl_xor(r, 32, 64);
        if (quad == 0)
            Dpart[((size_t)z * BB + b) * TT + s0 + st * 16 + l15] = r;
    }
}

// ---- kernel 3: xDT[b][e][s] = bf16(x[s][e] / sum_z Dpart[z][b][s]) ---------
__global__ __launch_bounds__(256) void xd_kernel(
        const __bf16* __restrict__ xb, const float* __restrict__ Dpart,
        __bf16* __restrict__ xDT) {
    __shared__ float Rs[64];
    __shared__ __bf16 tt[16][68];
    int b = blockIdx.y;
    int s0 = blockIdx.x * 64;
    int tid = threadIdx.x;
    if (tid < 64) {
        size_t si = (size_t)b * TT + s0 + tid;
        float d = Dpart[si];
#pragma unroll
        for (int zz = 1; zz < ZT; ++zz) d += Dpart[(size_t)zz * BB * TT + si];
        Rs[tid] = 1.0f / d;
    }
    __syncthreads();
    int sl = tid & 63, eg = tid >> 6;        // e-range eg*4..+3
    bf16x4 v = *(const bf16x4*)(xb + ((size_t)b * TT + s0 + sl) * EE + eg * 4);
    float r = Rs[sl];
#pragma unroll
    for (int i = 0; i < 4; ++i) tt[eg * 4 + i][sl] = (__bf16)((float)v[i] * r);
    __syncthreads();
    int e = tid >> 4, sc = tid & 15;
    *(bf16x4*)(xDT + ((size_t)b * EE + e) * TT + s0 + sc * 4) = *(const bf16x4*)&tt[e][sc * 4];
}

// ---- kernel 4: Z[z][b][t][e] = sum_{s in slice z} exp(S_ts) * xDT[e][s] ----
// R11: out = (E @ (x/D)) @ Wk — accumulate the 16-wide Z, apply Wk later.
// QK^T computed as S^T (A=xb rows s, B=Y cols t; R8's verified trick) so the
// E[t][s] transpose is one packed ds_write_b64 per (tile,ssub). Only the
// per-wave-private Etile uses LDS: NO barriers, NO staging. xb A-frag loads
// cover contiguous 512B; xDT B-frag rows are 16B-contiguous per lane.
__global__ __launch_bounds__(256) void out_mfma(
        const __bf16* __restrict__ Yb, const __bf16* __restrict__ xb,
        const __bf16* __restrict__ xDT, float* __restrict__ Z) {
    __shared__ __bf16 Etile[4][2][16 * 40]; // per-wave, per-tile E[t 16][s 32+pad8]

    int lane = threadIdx.x & 63;
    int w = threadIdx.x >> 6;
    int quad = lane >> 4;
    int l15 = lane & 15;
    int b = blockIdx.y;
    int z = blockIdx.z;
    int t0 = blockIdx.x * 128 + w * 32;

    const __bf16* xbb = xb + (size_t)b * TT * EE;
    const __bf16* Ybb = Yb + (size_t)b * TT * EE;
    const __bf16* xdb = xDT + (size_t)b * EE * TT;

    // persistent B of S^T: B[k=e][n=t] = Y[t0+tile*16+l15][quad*8..]; pad k>=16
    bf16x8 yf[2];
#pragma unroll
    for (int tile = 0; tile < 2; ++tile) {
        bf16x8 v = {};
        if (quad < 2)
            v = *(const bf16x8*)(Ybb + (size_t)(t0 + tile * 16 + l15) * EE + quad * 8);
        yf[tile] = v;
    }

    f32x4 acc[2] = {{0.f, 0.f, 0.f, 0.f}, {0.f, 0.f, 0.f, 0.f}};

    const int SL = TT / gridDim.z;
    int s0z = z * SL, send = s0z + SL;

    for (int s = s0z; s < send; s += 32) {
        // A of S^T: xb rows (m=s): contiguous 512B per ssub; pad k>=16
        bf16x8 af[2];
#pragma unroll
        for (int ss = 0; ss < 2; ++ss) {
            bf16x8 v = {};
            if (quad < 2)
                v = *(const bf16x8*)(xbb + (size_t)(s + ss * 16 + l15) * EE + quad * 8);
            af[ss] = v;
        }
        // B of PV: B[k=s_loc=quad*8+j][n=e=l15] = xDT[e=l15][s+quad*8..+7]
        bf16x8 bxd = *(const bf16x8*)(xdb + (size_t)l15 * TT + s + quad * 8);

#pragma unroll
        for (int tile = 0; tile < 2; ++tile) {
#pragma unroll
            for (int ss = 0; ss < 2; ++ss) {
                // S^T: row = s_loc = ss*16+quad*4+r, col = t_loc = l15
                f32x4 c = {0.f, 0.f, 0.f, 0.f};
                c = __builtin_amdgcn_mfma_f32_16x16x32_bf16(af[ss], yf[tile], c, 0, 0, 0);
                bf16x4 e;
#pragma unroll
                for (int r = 0; r < 4; ++r)
                    e[r] = (__bf16)exp_pow16(c[r]);
                *(bf16x4*)&Etile[w][tile][l15 * 40 + ss * 16 + quad * 4] = e;
            }
        }
        // PV: A[m=t=l15][k=s=quad*8+j] from Etile (compiler inserts the
        // RAW lgkmcnt; wave-private so no barrier; same-wave DS is in-order
        // so the next iteration's WAR on Etile is safe)
#pragma unroll
        for (int tile = 0; tile < 2; ++tile) {
            bf16x8 aE = *(const bf16x8*)&Etile[w][tile][l15 * 40 + quad * 8];
            acc[tile] = __builtin_amdgcn_mfma_f32_16x16x32_bf16(aE, bxd, acc[tile], 0, 0, 0);
        }
    }

    // Z: row = t0 + tile*16 + quad*4 + r, col = e = l15
    float* zp = Z + (((size_t)z * BB + b) * TT + t0) * EE;
#pragma unroll
    for (int tile = 0; tile < 2; ++tile)
#pragma unroll
        for (int r = 0; r < 4; ++r)
            zp[(size_t)(tile * 16 + quad * 4 + r) * EE + l15] = acc[tile][r];
}

// ---- kernel 5: out[b][t][h] = (sum_z Z[z][b][t][:]) @ Wk -------------------
__global__ __launch_bounds__(256) void zout_kernel(
        const float* __restrict__ Z, const float* __restrict__ Wk,
        float* __restrict__ out, int nslice) {
    __shared__ float zs[4][17];
    int b = blockIdx.y;
    int t0 = blockIdx.x * 4;
    int tid = threadIdx.x;
    if (tid < 64) {
        int tl = tid >> 4, e = tid & 15;
        float a = 0.f;
        for (int zz = 0; zz < nslice; ++zz)
            a += Z[(((size_t)zz * BB + b) * TT + t0 + tl) * EE + e];
        zs[tl][e] = a;
    }
    __syncthreads();
    int tl = tid >> 6, h = tid & 63;
    float o = 0.f;
#pragma unroll
    for (int e = 0; e < EE; ++e) o += zs[tl][e] * Wk[e * HH + h];
    out[((size_t)b * TT + t0 + tl) * HH + h] = o;
}

extern "C" void kernel_launch(void* const* d_in, const int* in_sizes, int n_in,
                              void* d_out, int out_size, void* d_ws, size_t ws_size,
                              hipStream_t stream) {
    const float* x  = (const float*)d_in[0];
    const float* Wq = (const float*)d_in[1];
    const float* Wk = (const float*)d_in[2];
    // d_in[3] (Wv) unused: reference computes v = x @ Wk (faithful quirk).

    const size_t NE16 = (size_t)BB * TT * EE;    // 524288
    char* wp = (char*)d_ws;
    __bf16* Yb    = (__bf16*)wp;  wp += NE16 * 2;                 // 1 MB
    __bf16* xbb   = (__bf16*)wp;  wp += NE16 * 2;                 // 1 MB
    __bf16* xDT   = (__bf16*)wp;  wp += NE16 * 2;                 // 1 MB
    float*  Dpart = (float*)wp;   wp += (size_t)ZT * BB * TT * 4; // 2 MB
    float*  Zws   = (float*)wp;

    size_t used = (size_t)(wp - (char*)d_ws);
    int nslice = 8;
    if (used + (size_t)8 * NE16 * 4 > ws_size) nslice = 4;
    if (used + (size_t)nslice * NE16 * 4 > ws_size) nslice = 2;

    float* out = (float*)d_out;

    proj_kernel<<<BB * TT / 16, 256, 0, stream>>>(x, Wq, Wk, Yb, xbb);
    colsum_mfma<<<dim3(TT / 256, BB, ZT), 256, 0, stream>>>(Yb, xbb, Dpart);
    xd_kernel<<<dim3(TT / 64, BB), 256, 0, stream>>>(xbb, Dpart, xDT);
    out_mfma<<<dim3(TT / 128, BB, nslice), 256, 0, stream>>>(Yb, xbb, xDT, Zws);
    zout_kernel<<<dim3(TT / 4, BB), 256, 0, stream>>>(Zws, Wk, out, nslice);
}

// Round 4
// 153.878 us; speedup vs baseline: 1.5719x; 1.0966x over previous
//
#include <hip/hip_runtime.h>
#include <hip/hip_bf16.h>

// Problem constants (from reference): B=8, T=4096, E=16, H=64
#define BB 8
#define TT 4096
#define EE 16
#define HH 64
#define ZT 16      // colsum t-chunk split: 2048 blocks = 8/CU
#define NS 8       // out_mfma s-slice split: 2048 blocks = 8/CU

typedef __attribute__((ext_vector_type(8))) __bf16 bf16x8;  // MFMA A/B frag (4 VGPRs)
typedef __attribute__((ext_vector_type(4))) __bf16 bf16x4;  // packed 8B
typedef __attribute__((ext_vector_type(4))) float f32x4;    // MFMA C/D frag

// e^(d^(-1/16)) ≈ P4(log2(d) - 5.5): degree-4 Taylor of exp(2^(-u/16)) about
// u=5.5. |rel err| < 2.5e-4 for d ∈ [2,1024] — inside bf16 noise (validated
// R6/R7). 1 transcendental + 5 VALU.
static __device__ __forceinline__ float exp_pow16(float d) {
    float t = __builtin_amdgcn_logf(d) - 5.5f;     // v_log_f32 = log2
    float r = __builtin_fmaf(t, 2.72889e-6f, -9.35716e-5f);
    r = __builtin_fmaf(t, r, 2.90736e-3f);
    r = __builtin_fmaf(t, r, -7.50656e-2f);
    r = __builtin_fmaf(t, r, 2.198967f);
    return r;
}

// ---- kernel 1: rank-16 factorization (R11) + zero Dpart --------------------
// S = Q K^T = x (Wq Wk^T) x^T — inner dim is E=16. Yb = bf16(x @ M),
// M = Wq Wk^T (per-block recompute, trivial), xb = bf16(x).
__global__ __launch_bounds__(256) void proj_kernel(
        const float* __restrict__ x, const float* __restrict__ Wq,
        const float* __restrict__ Wk,
        __bf16* __restrict__ Yb, __bf16* __restrict__ xb,
        float* __restrict__ Dsum) {
    __shared__ float Ms[16][16];
    __shared__ float xs[16][16];
    int tid = threadIdx.x;
    // zero Dsum (B*T floats = 8192 float4) before colsum (stream-ordered)
    size_t gid = (size_t)blockIdx.x * 256 + tid;
    if (gid < (size_t)BB * TT / 4)
        ((float4*)Dsum)[gid] = (float4){0.f, 0.f, 0.f, 0.f};
    int i = tid >> 4, j = tid & 15;
    float m = 0.f;
#pragma unroll 8
    for (int h = 0; h < HH; ++h) m += Wq[i * HH + h] * Wk[j * HH + h];
    Ms[i][j] = m;
    int row0 = blockIdx.x * 16;
    xs[i][j] = x[(size_t)(row0 + i) * EE + j];   // 256 consecutive floats
    __syncthreads();
    float y = 0.f;
#pragma unroll
    for (int k = 0; k < EE; ++k) y += xs[i][k] * Ms[k][j];
    size_t idx = (size_t)(row0 + i) * EE + j;
    Yb[idx] = (__bf16)y;
    xb[idx] = (__bf16)xs[i][j];
}

// ---- kernel 2: Dsum[b][s] += sum_{t in chunk z} exp((Y_t·x_s)^(-1/16)) -----
// R11 structure (zero LDS, zero barriers, 8 blocks/CU). R12: atomicAdd into a
// single [B][T] f32 buffer (L2-resident; ZT=16 contributions per address)
// instead of materializing ZT slices.
__global__ __launch_bounds__(256) void colsum_mfma(
        const __bf16* __restrict__ Yb, const __bf16* __restrict__ xb,
        float* __restrict__ Dsum) {
    int lane = threadIdx.x & 63;
    int w = threadIdx.x >> 6;
    int quad = lane >> 4;
    int l15 = lane & 15;
    int b = blockIdx.y;
    int z = blockIdx.z;
    int s0 = blockIdx.x * 256 + w * 64;

    const __bf16* xbb = xb + (size_t)b * TT * EE;
    const __bf16* Ybb = Yb + (size_t)b * TT * EE;

    // B[k=e][n=s]: lane holds xb[s0+st*16+l15][quad*8..+7]; k>=16 zero-padded
    bf16x8 bx[4];
#pragma unroll
    for (int st = 0; st < 4; ++st) {
        bf16x8 v = {};
        if (quad < 2)
            v = *(const bf16x8*)(xbb + (size_t)(s0 + st * 16 + l15) * EE + quad * 8);
        bx[st] = v;
    }

    const int TL = TT / ZT;                  // 256 t per block
    int t0 = z * TL, tend = t0 + TL;

    float csum[4] = {0.f, 0.f, 0.f, 0.f};
    for (int t = t0; t < tend; t += 32) {
        bf16x8 ya[2];                        // A[m=t][k=e], zero-padded k>=16
#pragma unroll
        for (int ts = 0; ts < 2; ++ts) {
            bf16x8 v = {};
            if (quad < 2)
                v = *(const bf16x8*)(Ybb + (size_t)(t + ts * 16 + l15) * EE + quad * 8);
            ya[ts] = v;
        }
#pragma unroll
        for (int st = 0; st < 4; ++st) {
#pragma unroll
            for (int ts = 0; ts < 2; ++ts) {
                f32x4 c = {0.f, 0.f, 0.f, 0.f};
                c = __builtin_amdgcn_mfma_f32_16x16x32_bf16(ya[ts], bx[st], c, 0, 0, 0);
                csum[st] += exp_pow16(c[0]) + exp_pow16(c[1])
                          + exp_pow16(c[2]) + exp_pow16(c[3]);
            }
        }
    }

    // C: row=t=quad*4+r (summed in-reg + cross-quad shuffle), col=s=l15
#pragma unroll
    for (int st = 0; st < 4; ++st) {
        float r = csum[st];
        r += __shfl_xor(r, 16, 64);
        r += __shfl_xor(r, 32, 64);
        if (quad == 0)
            atomicAdd(&Dsum[(size_t)b * TT + s0 + st * 16 + l15], r);
    }
}

// ---- kernel 3: xDT[b][e][s] = bf16(x[s][e] / Dsum[b][s]); zero Z -----------
__global__ __launch_bounds__(256) void xd_kernel(
        const __bf16* __restrict__ xb, const float* __restrict__ Dsum,
        __bf16* __restrict__ xDT, float* __restrict__ Z) {
    __shared__ float Rs[64];
    __shared__ __bf16 tt[16][68];
    int b = blockIdx.y;
    int s0 = blockIdx.x * 64;
    int tid = threadIdx.x;
    // zero Z (B*T*16 floats = 131072 float4 == gridDim total threads exactly)
    size_t zi = ((size_t)b * gridDim.x + blockIdx.x) * 256 + tid;
    ((float4*)Z)[zi] = (float4){0.f, 0.f, 0.f, 0.f};
    if (tid < 64)
        Rs[tid] = 1.0f / Dsum[(size_t)b * TT + s0 + tid];   // coalesced
    __syncthreads();
    int sl = tid & 63, eg = tid >> 6;        // e-range eg*4..+3
    bf16x4 v = *(const bf16x4*)(xb + ((size_t)b * TT + s0 + sl) * EE + eg * 4);
    float r = Rs[sl];
#pragma unroll
    for (int i = 0; i < 4; ++i) tt[eg * 4 + i][sl] = (__bf16)((float)v[i] * r);
    __syncthreads();
    int e = tid >> 4, sc = tid & 15;
    *(bf16x4*)(xDT + ((size_t)b * EE + e) * TT + s0 + sc * 4) = *(const bf16x4*)&tt[e][sc * 4];
}

// ---- kernel 4: Z[b][t][e] += sum_{s in slice z} exp(S_ts) * xDT[e][s] ------
// R11 structure (only per-wave-private Etile in LDS; no barriers/staging).
// R12: accumulate into the single 2MB Z via atomicAdd (8 contributions per
// address) instead of writing NS f32 slices (was 134 MB round-trip).
__global__ __launch_bounds__(256) void out_mfma(
        const __bf16* __restrict__ Yb, const __bf16* __restrict__ xb,
        const __bf16* __restrict__ xDT, float* __restrict__ Z) {
    __shared__ __bf16 Etile[4][2][16 * 40]; // per-wave, per-tile E[t 16][s 32+pad8]

    int lane = threadIdx.x & 63;
    int w = threadIdx.x >> 6;
    int quad = lane >> 4;
    int l15 = lane & 15;
    int b = blockIdx.y;
    int z = blockIdx.z;
    int t0 = blockIdx.x * 128 + w * 32;

    const __bf16* xbb = xb + (size_t)b * TT * EE;
    const __bf16* Ybb = Yb + (size_t)b * TT * EE;
    const __bf16* xdb = xDT + (size_t)b * EE * TT;

    // persistent B of S^T: B[k=e][n=t] = Y[t0+tile*16+l15][quad*8..]; pad k>=16
    bf16x8 yf[2];
#pragma unroll
    for (int tile = 0; tile < 2; ++tile) {
        bf16x8 v = {};
        if (quad < 2)
            v = *(const bf16x8*)(Ybb + (size_t)(t0 + tile * 16 + l15) * EE + quad * 8);
        yf[tile] = v;
    }

    f32x4 acc[2] = {{0.f, 0.f, 0.f, 0.f}, {0.f, 0.f, 0.f, 0.f}};

    const int SL = TT / NS;
    int s0z = z * SL, send = s0z + SL;

    for (int s = s0z; s < send; s += 32) {
        // A of S^T: xb rows (m=s): contiguous 512B per ssub; pad k>=16
        bf16x8 af[2];
#pragma unroll
        for (int ss = 0; ss < 2; ++ss) {
            bf16x8 v = {};
            if (quad < 2)
                v = *(const bf16x8*)(xbb + (size_t)(s + ss * 16 + l15) * EE + quad * 8);
            af[ss] = v;
        }
        // B of PV: B[k=s_loc=quad*8+j][n=e=l15] = xDT[e=l15][s+quad*8..+7]
        bf16x8 bxd = *(const bf16x8*)(xdb + (size_t)l15 * TT + s + quad * 8);

#pragma unroll
        for (int tile = 0; tile < 2; ++tile) {
#pragma unroll
            for (int ss = 0; ss < 2; ++ss) {
                // S^T: row = s_loc = ss*16+quad*4+r, col = t_loc = l15
                f32x4 c = {0.f, 0.f, 0.f, 0.f};
                c = __builtin_amdgcn_mfma_f32_16x16x32_bf16(af[ss], yf[tile], c, 0, 0, 0);
                bf16x4 e;
#pragma unroll
                for (int r = 0; r < 4; ++r)
                    e[r] = (__bf16)exp_pow16(c[r]);
                *(bf16x4*)&Etile[w][tile][l15 * 40 + ss * 16 + quad * 4] = e;
            }
        }
        // PV: A[m=t=l15][k=s=quad*8+j] from Etile (compiler inserts the RAW
        // lgkmcnt; wave-private so no barrier; same-wave DS in-order => WAR
        // on next iteration is safe)
#pragma unroll
        for (int tile = 0; tile < 2; ++tile) {
            bf16x8 aE = *(const bf16x8*)&Etile[w][tile][l15 * 40 + quad * 8];
            acc[tile] = __builtin_amdgcn_mfma_f32_16x16x32_bf16(aE, bxd, acc[tile], 0, 0, 0);
        }
    }

    // Z[t][e]: row = t0 + tile*16 + quad*4 + r, col = e = l15
    float* zp = Z + ((size_t)b * TT + t0) * EE;
#pragma unroll
    for (int tile = 0; tile < 2; ++tile)
#pragma unroll
        for (int r = 0; r < 4; ++r)
            atomicAdd(&zp[(size_t)(tile * 16 + quad * 4 + r) * EE + l15], acc[tile][r]);
}

// ---- kernel 5: out[b][t][h] = Z[b][t][:] @ Wk ------------------------------
// R12: fully coalesced — float4 Z loads (2MB total), LDS broadcast reads,
// per-thread Wk column in registers, coalesced out writes.
__global__ __launch_bounds__(256) void zout_kernel(
        const float* __restrict__ Z, const float* __restrict__ Wk,
        float* __restrict__ out) {
    __shared__ float zs[64][16];             // 64 t-rows x 16 e (flat-filled)
    int b = blockIdx.y;
    int t0 = blockIdx.x * 64;
    int tid = threadIdx.x;
    ((float4*)zs)[tid] = ((const float4*)(Z + ((size_t)b * TT + t0) * EE))[tid];
    __syncthreads();
    int h = tid & 63, tg = tid >> 6;
    float wcol[16];
#pragma unroll
    for (int e = 0; e < EE; ++e) wcol[e] = Wk[e * HH + h];
    float* ob = out + ((size_t)b * TT + t0) * HH + h;
#pragma unroll
    for (int k = 0; k < 16; ++k) {
        int tl = tg * 16 + k;
        float o = 0.f;
#pragma unroll
        for (int e = 0; e < EE; ++e) o = __builtin_fmaf(zs[tl][e], wcol[e], o);
        ob[(size_t)tl * HH] = o;             // all lanes read same zs row: broadcast
    }
}

extern "C" void kernel_launch(void* const* d_in, const int* in_sizes, int n_in,
                              void* d_out, int out_size, void* d_ws, size_t ws_size,
                              hipStream_t stream) {
    const float* x  = (const float*)d_in[0];
    const float* Wq = (const float*)d_in[1];
    const float* Wk = (const float*)d_in[2];
    // d_in[3] (Wv) unused: reference computes v = x @ Wk (faithful quirk).

    const size_t NE16 = (size_t)BB * TT * EE;    // 524288
    char* wp = (char*)d_ws;
    __bf16* Yb   = (__bf16*)wp;  wp += NE16 * 2;              // 1 MB
    __bf16* xbb  = (__bf16*)wp;  wp += NE16 * 2;              // 1 MB
    __bf16* xDT  = (__bf16*)wp;  wp += NE16 * 2;              // 1 MB
    float*  Dsum = (float*)wp;   wp += (size_t)BB * TT * 4;   // 128 KB
    float*  Zws  = (float*)wp;                                // 2 MB

    float* out = (float*)d_out;

    proj_kernel<<<BB * TT / 16, 256, 0, stream>>>(x, Wq, Wk, Yb, xbb, Dsum);
    colsum_mfma<<<dim3(TT / 256, BB, ZT), 256, 0, stream>>>(Yb, xbb, Dsum);
    xd_kernel<<<dim3(TT / 64, BB), 256, 0, stream>>>(xbb, Dsum, xDT, Zws);
    out_mfma<<<dim3(TT / 128, BB, NS), 256, 0, stream>>>(Yb, xbb, xDT, Zws);
    zout_kernel<<<dim3(TT / 64, BB), 256, 0, stream>>>(Zws, Wk, out);
}